// Round 7
// baseline (177.626 us; speedup 1.0000x reference)
//
#include <hip/hip_runtime.h>
#include <math.h>

#define BATCHES 128
#define T_LEN   32768
#define S_DIM   4
#define CHUNKS  32                            // 4096 blocks = 16/CU (2x oversubscribed)
#define BLOCK   256
#define TPT     4                             // consecutive t's per thread
#define NACC    21                            // D[16] + L1[4] + msum
#define LN2F    0.69314718055994530942f

// Hardware log2 (v_log_f32). Inputs are clipped to [1e-7, 1-1e-7] -> no edge cases.
__device__ __forceinline__ float hw_log2(float x) { return __builtin_amdgcn_logf(x); }

// Accumulate one timestep (all indexing static after inline+unroll).
__device__ __forceinline__ void accum1(
    const float4 pv, const float4 tv, const float m,
    float D[4][4], float L1[4], float& msum)
{
    const float pa[4] = {pv.x, pv.y, pv.z, pv.w};
    const float ta[4] = {tv.x, tv.y, tv.z, tv.w};
    float md[4];
    #pragma unroll
    for (int i = 0; i < 4; ++i) {
        const float p   = fminf(fmaxf(pa[i], 1e-7f), 1.0f - 1e-7f);
        const float lp  = hw_log2(p);            // log2(p)
        const float l1p = hw_log2(1.0f - p);     // 1-p exact for p>=0.5 (Sterbenz)
        md[i] = m * (lp - l1p);                  // m * logit (log2 domain)
        L1[i] = fmaf(m, l1p, L1[i]);
    }
    #pragma unroll
    for (int i = 0; i < 4; ++i)
        #pragma unroll
        for (int j = 0; j < 4; ++j)
            D[i][j] = fmaf(md[i], ta[j], D[i][j]);
    msum += m;
}

// Kernel 1: per-(batch,chunk) partial sums in log2 domain.
// Each thread owns 4 CONSECUTIVE t's: 4x float4 pred + 4x float4 targ +
// 1x float4 mask = 9 VMEM insts (was 12), each wave quartet spanning a
// contiguous 4 KB. 4096 blocks -> 16 blocks/CU: 2x residency oversubscription
// so a second generation of waves keeps issuing loads while the first stalls.
__global__ void pit_partial_kernel(
    const float* __restrict__ pred,
    const float* __restrict__ target,
    const float* __restrict__ mask,
    float* __restrict__ partial)   // [BATCHES][CHUNKS][NACC]
{
    const int b     = blockIdx.x / CHUNKS;
    const int chunk = blockIdx.x % CHUNKS;
    const int tid   = threadIdx.x;

    const float4* __restrict__ predv = (const float4*)(pred   + (size_t)b * T_LEN * S_DIM);
    const float4* __restrict__ targv = (const float4*)(target + (size_t)b * T_LEN * S_DIM);
    const float4* __restrict__ maskv = (const float4*)(mask   + (size_t)b * T_LEN);

    // Block covers BLOCK*TPT = 1024 consecutive t's.
    const int tbase = chunk * (BLOCK * TPT) + tid * TPT;

    const float4 P0 = predv[tbase + 0];
    const float4 P1 = predv[tbase + 1];
    const float4 P2 = predv[tbase + 2];
    const float4 P3 = predv[tbase + 3];
    const float4 T0 = targv[tbase + 0];
    const float4 T1 = targv[tbase + 1];
    const float4 T2 = targv[tbase + 2];
    const float4 T3 = targv[tbase + 3];
    const float4 MV = maskv[chunk * BLOCK + tid];   // 4 consecutive mask values

    float D[4][4] = {{0.f,0.f,0.f,0.f},{0.f,0.f,0.f,0.f},
                     {0.f,0.f,0.f,0.f},{0.f,0.f,0.f,0.f}};
    float L1[4]   = {0.f,0.f,0.f,0.f};
    float msum    = 0.f;

    accum1(P0, T0, MV.x, D, L1, msum);
    accum1(P1, T1, MV.y, D, L1, msum);
    accum1(P2, T2, MV.z, D, L1, msum);
    accum1(P3, T3, MV.w, D, L1, msum);

    // Pack accumulators (static indexing throughout — full unroll).
    float acc[NACC];
    #pragma unroll
    for (int i = 0; i < 4; ++i)
        #pragma unroll
        for (int j = 0; j < 4; ++j)
            acc[i * 4 + j] = D[i][j];
    #pragma unroll
    for (int i = 0; i < 4; ++i) acc[16 + i] = L1[i];
    acc[20] = msum;

    // Wave-64 shuffle reduction.
    #pragma unroll
    for (int k = 0; k < NACC; ++k) {
        float v = acc[k];
        #pragma unroll
        for (int off = 32; off >= 1; off >>= 1)
            v += __shfl_down(v, off, 64);
        acc[k] = v;
    }

    __shared__ float red[4][NACC];
    const int wave = tid >> 6;
    const int lane = tid & 63;
    if (lane == 0) {
        #pragma unroll
        for (int k = 0; k < NACC; ++k) red[wave][k] = acc[k];
    }
    __syncthreads();
    if (tid == 0) {
        float* __restrict__ dst = partial + ((size_t)b * CHUNKS + chunk) * NACC;
        #pragma unroll
        for (int k = 0; k < NACC; ++k)
            dst[k] = red[0][k] + red[1][k] + red[2][k] + red[3][k];
    }
}

// Kernel 2: one thread per batch — sum chunk partials, 24-perm max, mean.
__global__ __launch_bounds__(128) void pit_final_kernel(
    const float* __restrict__ partial,
    float* __restrict__ out)
{
    const int b = threadIdx.x;   // exactly BATCHES threads

    float acc[NACC];
    #pragma unroll
    for (int k = 0; k < NACC; ++k) acc[k] = 0.f;

    for (int c = 0; c < CHUNKS; ++c) {
        const float* __restrict__ src = partial + ((size_t)b * CHUNKS + c) * NACC;
        #pragma unroll
        for (int k = 0; k < NACC; ++k) acc[k] += src[k];
    }

    const float sumL1 = acc[16] + acc[17] + acc[18] + acc[19];
    const float msum  = acc[20];

    // max over all 24 permutations of sum_i D[i, perm[i]]  (log2 domain;
    // positive scaling by ln2 preserves the argmax)
    float best = -3.4e38f;
    #pragma unroll
    for (int i0 = 0; i0 < 4; ++i0) {
        #pragma unroll
        for (int i1 = 0; i1 < 4; ++i1) {
            if (i1 == i0) continue;
            #pragma unroll
            for (int i2 = 0; i2 < 4; ++i2) {
                if (i2 == i0 || i2 == i1) continue;
                const int i3 = 6 - i0 - i1 - i2;
                const float s = acc[0 * 4 + i0] + acc[1 * 4 + i1] +
                                acc[2 * 4 + i2] + acc[3 * 4 + i3];
                best = fmaxf(best, s);
            }
        }
    }

    // Convert log2-domain sums to natural-log domain with a single multiply.
    const float min_tot = -LN2F * (best + sumL1) / msum;          // min over perms of tot
    float contrib = min_tot * (1.0f / (S_DIM * BATCHES));         // /S then mean over B

    // Block reduce across 128 threads (2 waves).
    #pragma unroll
    for (int off = 32; off >= 1; off >>= 1)
        contrib += __shfl_down(contrib, off, 64);

    __shared__ float wsum[2];
    const int wave = threadIdx.x >> 6;
    const int lane = threadIdx.x & 63;
    if (lane == 0) wsum[wave] = contrib;
    __syncthreads();
    if (threadIdx.x == 0) out[0] = wsum[0] + wsum[1];
}

extern "C" void kernel_launch(void* const* d_in, const int* in_sizes, int n_in,
                              void* d_out, int out_size, void* d_ws, size_t ws_size,
                              hipStream_t stream) {
    const float* pred   = (const float*)d_in[0];
    const float* target = (const float*)d_in[1];
    const float* mask   = (const float*)d_in[2];
    float* out     = (float*)d_out;
    float* partial = (float*)d_ws;   // fully overwritten each launch; no memset needed

    pit_partial_kernel<<<BATCHES * CHUNKS, BLOCK, 0, stream>>>(pred, target, mask, partial);
    pit_final_kernel<<<1, 128, 0, stream>>>(partial, out);
}

// Round 8
// 171.193 us; speedup vs baseline: 1.0376x; 1.0376x over previous
//
#include <hip/hip_runtime.h>
#include <math.h>

#define BATCHES 128
#define T_LEN   32768
#define S_DIM   4
#define CHUNKS  16                    // blocks per batch
#define BLOCK   256                   // 4 waves
#define SPAN    (T_LEN / CHUNKS)      // 2048 t per block
#define TILE_T  256                   // t per tile (1 t per thread)
#define NTILES  (SPAN / TILE_T)       // 8
#define NSLOT   4                     // LDS ring depth
#define NACC    21                    // D[16] + L1[4] + msum
#define LN2F    0.69314718055994530942f

// Hardware log2 (v_log_f32). Inputs clipped to [1e-7, 1-1e-7] -> no edge cases.
__device__ __forceinline__ float hw_log2(float x) { return __builtin_amdgcn_logf(x); }

__device__ __forceinline__ void accum1(
    const float4 pv, const float4 tv, const float m,
    float D[4][4], float L1[4], float& msum)
{
    const float pa[4] = {pv.x, pv.y, pv.z, pv.w};
    const float ta[4] = {tv.x, tv.y, tv.z, tv.w};
    float md[4];
    #pragma unroll
    for (int i = 0; i < 4; ++i) {
        const float p   = fminf(fmaxf(pa[i], 1e-7f), 1.0f - 1e-7f);
        const float lp  = hw_log2(p);            // log2(p)
        const float l1p = hw_log2(1.0f - p);     // 1-p exact for p>=0.5 (Sterbenz)
        md[i] = m * (lp - l1p);                  // m * logit (log2 domain)
        L1[i] = fmaf(m, l1p, L1[i]);
    }
    #pragma unroll
    for (int i = 0; i < 4; ++i)
        #pragma unroll
        for (int j = 0; j < 4; ++j)
            D[i][j] = fmaf(md[i], ta[j], D[i][j]);
    msum += m;
}

// Kernel 1: LDS-ring streaming reduce with async global->LDS DMA.
// Compiler-proof MLP: global_load_lds is issued where written (no VGPR results
// to sink), drain depth controlled by hand-counted s_waitcnt vmcnt(N).
// Each wave stages AND consumes only its own 64-t quarter of each tile ->
// zero __syncthreads in the main loop; vmcnt is per-wave.
__global__ __launch_bounds__(BLOCK) void pit_partial_kernel(
    const float* __restrict__ pred,
    const float* __restrict__ target,
    const float* __restrict__ mask,
    float* __restrict__ partial)   // [BATCHES][CHUNKS][NACC]
{
    __shared__ float4 predS[NSLOT][TILE_T];   // 16 KB
    __shared__ float4 targS[NSLOT][TILE_T];   // 16 KB
    __shared__ float  maskS[NSLOT][TILE_T];   //  4 KB
    __shared__ float  red[4][NACC];

    const int b     = blockIdx.x / CHUNKS;
    const int chunk = blockIdx.x % CHUNKS;
    const int tid   = threadIdx.x;
    const int w64   = tid & ~63;              // wave base: 0,64,128,192 (uniform)
    const int lane  = tid & 63;

    const float4* __restrict__ predv = (const float4*)(pred   + (size_t)b * T_LEN * S_DIM);
    const float4* __restrict__ targv = (const float4*)(target + (size_t)b * T_LEN * S_DIM);
    const float*  __restrict__ maskb = mask + (size_t)b * T_LEN;

    const int tRow0 = chunk * SPAN;           // this block's first t within batch

    float D[4][4] = {{0.f,0.f,0.f,0.f},{0.f,0.f,0.f,0.f},
                     {0.f,0.f,0.f,0.f},{0.f,0.f,0.f,0.f}};
    float L1[4]   = {0.f,0.f,0.f,0.f};
    float msum    = 0.f;

// Stage tile k into slot k&3: 3 DMA insts per wave (pred 16B, targ 16B, mask 4B).
#define STAGE(k) do {                                                          \
    const int idx = tRow0 + (k) * TILE_T + w64 + lane;                         \
    __builtin_amdgcn_global_load_lds(                                          \
        (const __attribute__((address_space(1))) void*)(predv + idx),          \
        (__attribute__((address_space(3))) void*)(&predS[(k) & 3][w64]),       \
        16, 0, 0);                                                             \
    __builtin_amdgcn_global_load_lds(                                          \
        (const __attribute__((address_space(1))) void*)(targv + idx),          \
        (__attribute__((address_space(3))) void*)(&targS[(k) & 3][w64]),       \
        16, 0, 0);                                                             \
    __builtin_amdgcn_global_load_lds(                                          \
        (const __attribute__((address_space(1))) void*)(maskb + idx),          \
        (__attribute__((address_space(3))) void*)(&maskS[(k) & 3][w64]),       \
        4, 0, 0);                                                              \
} while (0)

// Wait until at most N of MY wave's DMA ops remain in flight (in-order retire).
#define WAITVM(n) asm volatile("s_waitcnt vmcnt(" #n ")" ::: "memory")

// Consume tile k from slot k&3 (each thread its own t). Trailing lgkmcnt(0)
// guarantees ds_reads completed before this slot is re-staged 4 tiles later.
#define COMP(k) do {                                                           \
    const float4 pv = predS[(k) & 3][tid];                                     \
    const float4 tv = targS[(k) & 3][tid];                                     \
    const float  mv = maskS[(k) & 3][tid];                                     \
    accum1(pv, tv, mv, D, L1, msum);                                           \
    asm volatile("s_waitcnt lgkmcnt(0)" ::: "memory");                         \
} while (0)

    // Depth-4 pipeline: 3 tiles (9 insts, 9 KB) permanently in flight per wave.
    STAGE(0); STAGE(1); STAGE(2);
    STAGE(3); WAITVM(9); COMP(0);
    STAGE(4); WAITVM(9); COMP(1);
    STAGE(5); WAITVM(9); COMP(2);
    STAGE(6); WAITVM(9); COMP(3);
    STAGE(7); WAITVM(9); COMP(4);
    WAITVM(6); COMP(5);
    WAITVM(3); COMP(6);
    WAITVM(0); COMP(7);

#undef STAGE
#undef WAITVM
#undef COMP

    // Pack accumulators (static indexing throughout — full unroll).
    float acc[NACC];
    #pragma unroll
    for (int i = 0; i < 4; ++i)
        #pragma unroll
        for (int j = 0; j < 4; ++j)
            acc[i * 4 + j] = D[i][j];
    #pragma unroll
    for (int i = 0; i < 4; ++i) acc[16 + i] = L1[i];
    acc[20] = msum;

    // Wave-64 shuffle reduction.
    #pragma unroll
    for (int k = 0; k < NACC; ++k) {
        float v = acc[k];
        #pragma unroll
        for (int off = 32; off >= 1; off >>= 1)
            v += __shfl_down(v, off, 64);
        acc[k] = v;
    }

    const int wave = tid >> 6;
    if (lane == 0) {
        #pragma unroll
        for (int k = 0; k < NACC; ++k) red[wave][k] = acc[k];
    }
    __syncthreads();
    if (tid == 0) {
        float* __restrict__ dst = partial + ((size_t)b * CHUNKS + chunk) * NACC;
        #pragma unroll
        for (int k = 0; k < NACC; ++k)
            dst[k] = red[0][k] + red[1][k] + red[2][k] + red[3][k];
    }
}

// Kernel 2: one thread per batch — sum chunk partials, 24-perm max, mean.
__global__ __launch_bounds__(128) void pit_final_kernel(
    const float* __restrict__ partial,
    float* __restrict__ out)
{
    const int b = threadIdx.x;   // exactly BATCHES threads

    float acc[NACC];
    #pragma unroll
    for (int k = 0; k < NACC; ++k) acc[k] = 0.f;

    for (int c = 0; c < CHUNKS; ++c) {
        const float* __restrict__ src = partial + ((size_t)b * CHUNKS + c) * NACC;
        #pragma unroll
        for (int k = 0; k < NACC; ++k) acc[k] += src[k];
    }

    const float sumL1 = acc[16] + acc[17] + acc[18] + acc[19];
    const float msum  = acc[20];

    // max over all 24 permutations of sum_i D[i, perm[i]]  (log2 domain;
    // positive scaling by ln2 preserves the argmax)
    float best = -3.4e38f;
    #pragma unroll
    for (int i0 = 0; i0 < 4; ++i0) {
        #pragma unroll
        for (int i1 = 0; i1 < 4; ++i1) {
            if (i1 == i0) continue;
            #pragma unroll
            for (int i2 = 0; i2 < 4; ++i2) {
                if (i2 == i0 || i2 == i1) continue;
                const int i3 = 6 - i0 - i1 - i2;
                const float s = acc[0 * 4 + i0] + acc[1 * 4 + i1] +
                                acc[2 * 4 + i2] + acc[3 * 4 + i3];
                best = fmaxf(best, s);
            }
        }
    }

    // Convert log2-domain sums to natural-log domain with a single multiply.
    const float min_tot = -LN2F * (best + sumL1) / msum;          // min over perms of tot
    float contrib = min_tot * (1.0f / (S_DIM * BATCHES));         // /S then mean over B

    // Block reduce across 128 threads (2 waves).
    #pragma unroll
    for (int off = 32; off >= 1; off >>= 1)
        contrib += __shfl_down(contrib, off, 64);

    __shared__ float wsum[2];
    const int wave = threadIdx.x >> 6;
    const int lane = threadIdx.x & 63;
    if (lane == 0) wsum[wave] = contrib;
    __syncthreads();
    if (threadIdx.x == 0) out[0] = wsum[0] + wsum[1];
}

extern "C" void kernel_launch(void* const* d_in, const int* in_sizes, int n_in,
                              void* d_out, int out_size, void* d_ws, size_t ws_size,
                              hipStream_t stream) {
    const float* pred   = (const float*)d_in[0];
    const float* target = (const float*)d_in[1];
    const float* mask   = (const float*)d_in[2];
    float* out     = (float*)d_out;
    float* partial = (float*)d_ws;   // fully overwritten each launch; no memset needed

    pit_partial_kernel<<<BATCHES * CHUNKS, BLOCK, 0, stream>>>(pred, target, mask, partial);
    pit_final_kernel<<<1, 128, 0, stream>>>(partial, out);
}

// Round 10
// 158.475 us; speedup vs baseline: 1.1208x; 1.0803x over previous
//
#include <hip/hip_runtime.h>
#include <math.h>

#define BATCHES 128
#define T_LEN   32768
#define S_DIM   4
#define CHUNKS  16
#define BLOCK   256
#define ITERS   (T_LEN / (CHUNKS * BLOCK))   // 8
#define NACC    21                            // D[16] + L1[4] + msum
#define LN2F    0.69314718055994530942f

// Native clang vector type: __builtin_nontemporal_load accepts pointers to
// these (it rejects HIP_vector_type<float,4>, which is a struct).
typedef float vfloat4 __attribute__((ext_vector_type(4)));

// Hardware log2 (v_log_f32). Inputs clipped to [1e-7, 1-1e-7] -> no edge cases.
__device__ __forceinline__ float hw_log2(float x) { return __builtin_amdgcn_logf(x); }

__device__ __forceinline__ void accum1(
    const vfloat4 pv, const vfloat4 tv, const float m,
    float D[4][4], float L1[4], float& msum)
{
    const float pa[4] = {pv.x, pv.y, pv.z, pv.w};
    const float ta[4] = {tv.x, tv.y, tv.z, tv.w};
    float md[4];
    #pragma unroll
    for (int i = 0; i < 4; ++i) {
        const float p   = fminf(fmaxf(pa[i], 1e-7f), 1.0f - 1e-7f);
        const float lp  = hw_log2(p);            // log2(p)
        const float l1p = hw_log2(1.0f - p);     // 1-p exact for p>=0.5 (Sterbenz)
        md[i] = m * (lp - l1p);                  // m * logit (log2 domain)
        L1[i] = fmaf(m, l1p, L1[i]);
    }
    #pragma unroll
    for (int i = 0; i < 4; ++i)
        #pragma unroll
        for (int j = 0; j < 4; ++j)
            D[i][j] = fmaf(md[i], ta[j], D[i][j]);
    msum += m;
}

// Kernel 1: per-(batch,chunk) partial sums in log2 domain.
// Simplest unit-stride structure + NON-TEMPORAL loads (nt flag): zero-reuse
// 151 MB stream should not allocate in L2/L3 on miss. This is the last
// un-falsified hypothesis for the ~2.77 TB/s read-path ceiling observed
// across 5 structural variants (register ILP, DMA ring, occupancy, grid).
__global__ __launch_bounds__(BLOCK) void pit_partial_kernel(
    const float* __restrict__ pred,
    const float* __restrict__ target,
    const float* __restrict__ mask,
    float* __restrict__ partial)   // [BATCHES][CHUNKS][NACC]
{
    const int b     = blockIdx.x / CHUNKS;
    const int chunk = blockIdx.x % CHUNKS;
    const int tid   = threadIdx.x;

    const vfloat4* __restrict__ predv = (const vfloat4*)(pred   + (size_t)b * T_LEN * S_DIM);
    const vfloat4* __restrict__ targv = (const vfloat4*)(target + (size_t)b * T_LEN * S_DIM);
    const float*   __restrict__ maskb = mask + (size_t)b * T_LEN;

    const int t0 = chunk * (T_LEN / CHUNKS) + tid;   // 8 t's per thread, stride BLOCK

    float D[4][4] = {{0.f,0.f,0.f,0.f},{0.f,0.f,0.f,0.f},
                     {0.f,0.f,0.f,0.f},{0.f,0.f,0.f,0.f}};
    float L1[4]   = {0.f,0.f,0.f,0.f};
    float msum    = 0.f;

    #pragma unroll
    for (int it = 0; it < ITERS; ++it) {
        const int t = t0 + it * BLOCK;
        const vfloat4 pv = __builtin_nontemporal_load(predv + t);
        const vfloat4 tv = __builtin_nontemporal_load(targv + t);
        const float   m  = __builtin_nontemporal_load(maskb + t);
        accum1(pv, tv, m, D, L1, msum);
    }

    // Pack accumulators (static indexing throughout — full unroll).
    float acc[NACC];
    #pragma unroll
    for (int i = 0; i < 4; ++i)
        #pragma unroll
        for (int j = 0; j < 4; ++j)
            acc[i * 4 + j] = D[i][j];
    #pragma unroll
    for (int i = 0; i < 4; ++i) acc[16 + i] = L1[i];
    acc[20] = msum;

    // Wave-64 shuffle reduction.
    #pragma unroll
    for (int k = 0; k < NACC; ++k) {
        float v = acc[k];
        #pragma unroll
        for (int off = 32; off >= 1; off >>= 1)
            v += __shfl_down(v, off, 64);
        acc[k] = v;
    }

    __shared__ float red[4][NACC];
    const int wave = tid >> 6;
    const int lane = tid & 63;
    if (lane == 0) {
        #pragma unroll
        for (int k = 0; k < NACC; ++k) red[wave][k] = acc[k];
    }
    __syncthreads();
    if (tid == 0) {
        float* __restrict__ dst = partial + ((size_t)b * CHUNKS + chunk) * NACC;
        #pragma unroll
        for (int k = 0; k < NACC; ++k)
            dst[k] = red[0][k] + red[1][k] + red[2][k] + red[3][k];
    }
}

// Kernel 2: one thread per batch — sum chunk partials, 24-perm max, mean.
__global__ __launch_bounds__(128) void pit_final_kernel(
    const float* __restrict__ partial,
    float* __restrict__ out)
{
    const int b = threadIdx.x;   // exactly BATCHES threads

    float acc[NACC];
    #pragma unroll
    for (int k = 0; k < NACC; ++k) acc[k] = 0.f;

    for (int c = 0; c < CHUNKS; ++c) {
        const float* __restrict__ src = partial + ((size_t)b * CHUNKS + c) * NACC;
        #pragma unroll
        for (int k = 0; k < NACC; ++k) acc[k] += src[k];
    }

    const float sumL1 = acc[16] + acc[17] + acc[18] + acc[19];
    const float msum  = acc[20];

    // max over all 24 permutations of sum_i D[i, perm[i]]  (log2 domain;
    // positive scaling by ln2 preserves the argmax)
    float best = -3.4e38f;
    #pragma unroll
    for (int i0 = 0; i0 < 4; ++i0) {
        #pragma unroll
        for (int i1 = 0; i1 < 4; ++i1) {
            if (i1 == i0) continue;
            #pragma unroll
            for (int i2 = 0; i2 < 4; ++i2) {
                if (i2 == i0 || i2 == i1) continue;
                const int i3 = 6 - i0 - i1 - i2;
                const float s = acc[0 * 4 + i0] + acc[1 * 4 + i1] +
                                acc[2 * 4 + i2] + acc[3 * 4 + i3];
                best = fmaxf(best, s);
            }
        }
    }

    // Convert log2-domain sums to natural-log domain with a single multiply.
    const float min_tot = -LN2F * (best + sumL1) / msum;          // min over perms of tot
    float contrib = min_tot * (1.0f / (S_DIM * BATCHES));         // /S then mean over B

    // Block reduce across 128 threads (2 waves).
    #pragma unroll
    for (int off = 32; off >= 1; off >>= 1)
        contrib += __shfl_down(contrib, off, 64);

    __shared__ float wsum[2];
    const int wave = threadIdx.x >> 6;
    const int lane = threadIdx.x & 63;
    if (lane == 0) wsum[wave] = contrib;
    __syncthreads();
    if (threadIdx.x == 0) out[0] = wsum[0] + wsum[1];
}

extern "C" void kernel_launch(void* const* d_in, const int* in_sizes, int n_in,
                              void* d_out, int out_size, void* d_ws, size_t ws_size,
                              hipStream_t stream) {
    const float* pred   = (const float*)d_in[0];
    const float* target = (const float*)d_in[1];
    const float* mask   = (const float*)d_in[2];
    float* out     = (float*)d_out;
    float* partial = (float*)d_ws;   // fully overwritten each launch; no memset needed

    pit_partial_kernel<<<BATCHES * CHUNKS, BLOCK, 0, stream>>>(pred, target, mask, partial);
    pit_final_kernel<<<1, 128, 0, stream>>>(partial, out);
}